// Round 14
// baseline (199.426 us; speedup 1.0000x reference)
//
#include <hip/hip_runtime.h>
#include <math.h>

#define BATCH 4
#define NCH 4
#define H 160
#define W 160
#define NPIX (H * W)          // 25600
#define NTILE (NPIX / 256)    // 100 tiles of 256 pixels
#define PRE_K 2048
#define TOPK 500
#define PROB_T 0.75f
#define IOU_T 0.5f
#define COV 10.0f

// ---- workspace layout (bytes) ----
#define KEY_OFF   0u                 // u64   [B][NPIX]  keys (0 = non-frontal)
#define F_OFF     819200u            // int   [B]
#define CSC_OFF   819264u            // float [B][PRE_K]
#define CBOX_OFF  852032u            // float [B][PRE_K][4]
#define SUP_OFF   983104u            // u32   [B][PRE_K][64]
#define NV_OFF    3080256u           // int   [B]
#define PAR_OFF   3080320u           // float [B][TOPK][5]
#define FLAG_OFF  3120320u           // u8    [B][PRE_K]
#define BCNT_OFF  3128512u           // int   [B][NTILE]

// out layout (floats)
#define OUT_HEAT_OFF 0
#define OUT_MASK_OFF 102400
#define OUT_BOX_OFF  512000
#define OUT_VAL_OFF  520000

typedef unsigned long long u64;
typedef unsigned int u32;

// -------- block exclusive scan over 256 ints (used by finalize phase) --------
__device__ __forceinline__ int block_scan_excl(int v, int tid, int* tmp, int* total) {
    tmp[tid] = v;
    __syncthreads();
    for (int off = 1; off < 256; off <<= 1) {
        int y = (tid >= off) ? tmp[tid - off] : 0;
        __syncthreads();
        tmp[tid] += y;
        __syncthreads();
    }
    int incl = tmp[tid];
    *total = tmp[255];
    __syncthreads();
    return incl - v;
}

// K1: softmax-max / frontal test -> u64 key (0 for non-frontal) + mask copy +
// per-tile frontal count. key = (score_bits<<32)|(0x7FFFFFFF-idx): positive
// float bits compare unsigned like floats, so key_j > key_i  <=>  JAX top_k order.
__global__ void k_score(const float* __restrict__ mask, u64* __restrict__ keys,
                        float* __restrict__ out_mask, int* __restrict__ blkcnt) {
    int b = blockIdx.y;
    int pix = blockIdx.x * 256 + threadIdx.x;
    const float* mp = mask + (size_t)b * NCH * NPIX + pix;
    float* op = out_mask + (size_t)b * NCH * NPIX + pix;
    float x0 = mp[0], x1 = mp[NPIX], x2 = mp[2 * NPIX], x3 = mp[3 * NPIX];
    op[0] = x0; op[NPIX] = x1; op[2 * NPIX] = x2; op[3 * NPIX] = x3;
    float m = x0; int c = 0;
    if (x1 > m) { m = x1; c = 1; }
    if (x2 > m) { m = x2; c = 2; }
    if (x3 > m) { m = x3; c = 3; }
    float sum = ((expf(x0 - m) + expf(x1 - m)) + expf(x2 - m)) + expf(x3 - m);
    float prob = 1.0f / sum;
    bool frontal = (c != 0) && (prob > PROB_T);
    u64 key = frontal
        ? (((u64)__float_as_uint(prob) << 32) | (u64)(0x7FFFFFFFu - (u32)pix))
        : 0ull;
    keys[(size_t)b * NPIX + pix] = key;
    __shared__ int wcnt[4];
    u64 bm = __ballot(frontal);
    if ((threadIdx.x & 63) == 0) wcnt[threadIdx.x >> 6] = __popcll(bm);
    __syncthreads();
    if (threadIdx.x == 0)
        blkcnt[b * NTILE + blockIdx.x] = wcnt[0] + wcnt[1] + wcnt[2] + wcnt[3];
}

// K2: rank + padding, NO compaction stage. Each block handles its own tile:
// (a) padding candidates from blkcnt prefixes, (b) exact rank of its frontal
// pixels by wave-parallel scan of the FULL key array (coalesced, L2-hot;
// non-frontal keys are 0, below every frontal key).
__global__ void __launch_bounds__(256)
k_rankpad(const u64* __restrict__ keys, const float* __restrict__ bias,
          const int* __restrict__ blkcnt, int* __restrict__ Fout,
          float* __restrict__ cand_score, float* __restrict__ cand_box) {
    int b = blockIdx.y;
    int bx = blockIdx.x;
    int tid = threadIdx.x;
    int lane = tid & 63, wv = tid >> 6;
    const int* bc = blkcnt + b * NTILE;
    const float* bb = bias + (size_t)b * 4 * NPIX;
    int F = 0, f_base = 0;
    #pragma unroll 4
    for (int k = 0; k < NTILE; ++k) {
        int c = bc[k];
        F += c;
        if (k < bx) f_base += c;
    }
    if (bx == 0 && tid == 0) Fout[b] = F;
    int pix = bx * 256 + tid;
    u64 myk = keys[(size_t)b * NPIX + pix];
    int fr = (myk != 0ull) ? 1 : 0;
    // block-local ordered scan of fr
    int incl = fr;
    for (int off = 1; off < 64; off <<= 1) {
        int y = __shfl_up(incl, off);
        if (lane >= off) incl += y;
    }
    __shared__ int wtot[4], wpre[5];
    __shared__ u64 items[256];
    if (lane == 63) wtot[wv] = incl;
    __syncthreads();
    if (tid == 0) {
        int acc = 0;
        for (int k = 0; k < 4; ++k) { wpre[k] = acc; acc += wtot[k]; }
        wpre[4] = acc;
    }
    __syncthreads();
    int f_local = wpre[wv] + (incl - fr);
    if (fr) items[f_local] = myk;
    // padding: first (PRE_K - F) non-frontal pixels in raster order
    if (!fr && F < PRE_K) {
        int slot = F + (pix - f_base - f_local);
        if (slot < PRE_K) {
            cand_score[(size_t)b * PRE_K + slot] = -1.0f;
            float y = (float)(pix / W), x = (float)(pix % W);
            float4 box;
            box.x = y + bb[0 * NPIX + pix];
            box.y = x + bb[1 * NPIX + pix];
            box.z = y + bb[2 * NPIX + pix];
            box.w = x + bb[3 * NPIX + pix];
            ((float4*)cand_box)[(size_t)b * PRE_K + slot] = box;
        }
    }
    __syncthreads();
    int nI = wpre[4];
    // ranking: wave wv handles items wv, wv+4, ...
    const u64* kb = keys + (size_t)b * NPIX;
    for (int it = wv; it < nI; it += 4) {
        u64 ki = items[it];
        int cnt = 0;
        for (int j0 = 0; j0 < NPIX; j0 += 256) {
            cnt += (kb[j0 + lane]       > ki) ? 1 : 0;
            cnt += (kb[j0 + 64 + lane]  > ki) ? 1 : 0;
            cnt += (kb[j0 + 128 + lane] > ki) ? 1 : 0;
            cnt += (kb[j0 + 192 + lane] > ki) ? 1 : 0;
        }
        for (int off = 32; off > 0; off >>= 1) cnt += __shfl_down(cnt, off);
        if (lane == 0 && cnt < PRE_K) {
            int rank = cnt;
            float si = __uint_as_float((u32)(ki >> 32));
            int xi = 0x7FFFFFFF - (int)(u32)(ki & 0xFFFFFFFFu);
            cand_score[(size_t)b * PRE_K + rank] = si;
            float y = (float)(xi / W), x = (float)(xi % W);
            float4 box;
            box.x = y + bb[0 * NPIX + xi];
            box.y = x + bb[1 * NPIX + xi];
            box.z = y + bb[2 * NPIX + xi];
            box.w = x + bb[3 * NPIX + xi];
            ((float4*)cand_box)[(size_t)b * PRE_K + rank] = box;
        }
    }
}

// K3: suppression bitmatrix, u32 granularity, row-contiguous; per-row nonzero flag.
// Strips entirely >= V exit early (NMS only consults rows < V).
__global__ void __launch_bounds__(512)
k_iou(const float* __restrict__ cand_box, const int* __restrict__ Fout,
      u32* __restrict__ sup, unsigned char* __restrict__ flag) {
    int b = blockIdx.y;
    int F = Fout[b];
    int V = F < PRE_K ? F : PRE_K;
    int r0 = blockIdx.x * 8;
    if (r0 >= V) return;
    __shared__ float ly1[PRE_K], lx1[PRE_K], ly2[PRE_K], lx2[PRE_K], lar[PRE_K];
    for (int k = threadIdx.x; k < PRE_K; k += 512) {
        float4 v = ((const float4*)cand_box)[(size_t)b * PRE_K + k];
        ly1[k] = v.x; lx1[k] = v.y; ly2[k] = v.z; lx2[k] = v.w;
        lar[k] = (v.z - v.x) * (v.w - v.y);
    }
    __syncthreads();
    int lr = threadIdx.x >> 6;      // 0..7 (one wave per row)
    int w = threadIdx.x & 63;       // 0..63 word lane
    int i = r0 + lr;
    float ay1 = ly1[i], ax1 = lx1[i], ay2 = ly2[i], ax2 = lx2[i], aa = lar[i];
    u32 bits = 0;
    int jbase = w * 32;
    #pragma unroll 4
    for (int jj = 0; jj < 32; ++jj) {
        int jo = (jj + w) & 31;             // bank-conflict-free rotation
        int j = jbase + jo;
        if (j > i) {
            float lty = fmaxf(ay1, ly1[j]);
            float ltx = fmaxf(ax1, lx1[j]);
            float rby = fminf(ay2, ly2[j]);
            float rbx = fminf(ax2, lx2[j]);
            float wy = fmaxf(rby - lty, 0.0f);
            float wx = fmaxf(rbx - ltx, 0.0f);
            float inter = wy * wx;
            float iou = inter / ((aa + lar[j]) - inter);
            if (iou > IOU_T) bits |= (1u << jo);
        }
    }
    sup[((size_t)b * PRE_K + i) * 64 + w] = bits;
    bool any = __any(bits != 0u);
    if (w == 0) flag[(size_t)b * PRE_K + i] = any ? 1 : 0;
}

// K4: fused NMS + finalize. Wave 0: sparse greedy NMS over ordered nonzero rows
// (4-chunk x 8-row register ring pipeline, readlane keep checks); then all 256
// threads do the top-500 compaction, outputs, and heat params.
__global__ void __launch_bounds__(256)
k_nmsfin(const u32* __restrict__ sup, const unsigned char* __restrict__ flag,
         const int* __restrict__ Fout, const float* __restrict__ cand_score,
         const float* __restrict__ cand_box, float* __restrict__ out_boxes,
         float* __restrict__ out_valid, float* __restrict__ params,
         int* __restrict__ NV) {
    int b = blockIdx.x;
    int tid = threadIdx.x;
    int F = Fout[b];
    int V = F < PRE_K ? F : PRE_K;
    __shared__ int rid_s[PRE_K];
    __shared__ int M_s;
    __shared__ u32 kws[64];
    __shared__ int tmp[256];

    if (tid < 64) {
        int lane = tid;
        const u32* f32 = (const u32*)(flag + (size_t)b * PRE_K);
        u32 fw[8];
        #pragma unroll
        for (int k = 0; k < 8; ++k) fw[k] = f32[lane * 8 + k];
        int r0 = lane * 32;
        int cnt = 0;
        #pragma unroll
        for (int k = 0; k < 8; ++k)
            #pragma unroll
            for (int j = 0; j < 4; ++j) {
                int r = r0 + k * 4 + j;
                if (((fw[k] >> (8 * j)) & 0xFFu) != 0u && r < V) ++cnt;
            }
        int incl = cnt;
        for (int off = 1; off < 64; off <<= 1) {
            int y = __shfl_up(incl, off);
            if (lane >= off) incl += y;
        }
        if (lane == 63) M_s = incl;
        int pos = incl - cnt;
        #pragma unroll
        for (int k = 0; k < 8; ++k)
            #pragma unroll
            for (int j = 0; j < 4; ++j) {
                int r = r0 + k * 4 + j;
                if (((fw[k] >> (8 * j)) & 0xFFu) != 0u && r < V) rid_s[pos++] = r;
            }
    }
    __syncthreads();

    if (tid < 64) {
        int lane = tid;
        int M = M_s;
        int rem = V - lane * 32;
        u32 kw = (rem >= 32) ? 0xFFFFFFFFu : (rem <= 0 ? 0u : ((1u << rem) - 1u));
        const u32* supb = sup + (size_t)b * PRE_K * 64 + lane;  // lane = word index
        int C = (M + 7) >> 3;
        int C4 = (C + 3) & ~3;
        int l7 = lane & 7;
        u32 rbuf[4][8];
        int ridv[4];

        #define LOAD_RID(slot, c) ridv[slot] = rid_s[min((c) * 8 + l7, PRE_K - 1)]
        #define ISSUE(slot) do { \
            _Pragma("unroll") \
            for (int k_ = 0; k_ < 8; ++k_) { \
                int i_ = __builtin_amdgcn_readlane(ridv[slot], k_) & (PRE_K - 1); \
                rbuf[slot][k_] = supb[(size_t)i_ * 64]; \
            } \
        } while (0)
        #define PROC(slot, c) do { \
            _Pragma("unroll") \
            for (int k_ = 0; k_ < 8; ++k_) { \
                int m_ = (c) * 8 + k_; \
                if (m_ < M) { \
                    int i_ = __builtin_amdgcn_readlane(ridv[slot], k_) & (PRE_K - 1); \
                    u32 kb_ = (u32)__builtin_amdgcn_readlane((int)kw, i_ >> 5); \
                    if ((kb_ >> (i_ & 31)) & 1u) kw &= ~rbuf[slot][k_]; \
                } \
            } \
        } while (0)

        LOAD_RID(0, 0); LOAD_RID(1, 1); LOAD_RID(2, 2); LOAD_RID(3, 3);
        ISSUE(0); ISSUE(1); ISSUE(2);
        for (int c = 0; c < C4; c += 4) {
            PROC(0, c);     ISSUE(3);            LOAD_RID(0, c + 4);
            PROC(1, c + 1); ISSUE(0);            LOAD_RID(1, c + 5);
            PROC(2, c + 2); ISSUE(1);            LOAD_RID(2, c + 6);
            PROC(3, c + 3); ISSUE(2);            LOAD_RID(3, c + 7);
        }
        #undef LOAD_RID
        #undef ISSUE
        #undef PROC
        kws[lane] = kw;
    }
    __syncthreads();

    int s0 = tid * 8;
    int bits8 = (int)((kws[s0 >> 5] >> (s0 & 31)) & 0xFFu);
    int cnt = __popc(bits8);
    int tot;
    int kpre = block_scan_excl(cnt, tid, tmp, &tot);
    int NK = tot;
    for (int k = 0; k < 8; ++k) {
        int s = s0 + k;
        int kept = (bits8 >> k) & 1;
        int pos = kept ? kpre : (NK + s - kpre);
        if (pos < TOPK) {
            float4 bx = ((const float4*)cand_box)[(size_t)b * PRE_K + s];
            ((float4*)out_boxes)[(size_t)b * TOPK + pos] = bx;
            out_valid[(size_t)b * TOPK + pos] = kept ? 1.0f : 0.0f;
            if (kept) {
                float scv = cand_score[(size_t)b * PRE_K + s];
                float* pp = params + ((size_t)b * TOPK + pos) * 5;
                pp[0] = (bx.x + bx.z) * 0.5f;   // muy
                pp[1] = (bx.y + bx.w) * 0.5f;   // mux
                pp[2] = (bx.z - bx.x) / COV;    // sigma_y / cov
                pp[3] = (bx.w - bx.y) / COV;    // sigma_x / cov
                pp[4] = scv;                    // prob
            }
        }
        kpre += kept;
    }
    if (tid == 0) NV[b] = NK < TOPK ? NK : TOPK;
}

// K5: tiled heat map with per-tile Gaussian culling.
#define TILE 16
#define TPL (W / TILE)   // 10 tiles per row
__global__ void k_heat(const float* __restrict__ params, const int* __restrict__ NV,
                       float* __restrict__ heat) {
    int b = blockIdx.y;
    int ty0 = (blockIdx.x / TPL) * TILE;
    int tx0 = (blockIdx.x % TPL) * TILE;
    int tid = threadIdx.x;
    int nv = NV[b];
    __shared__ float lp[TOPK * 5];
    __shared__ int cntS;
    if (tid == 0) cntS = 0;
    __syncthreads();
    for (int t = tid; t < nv; t += 256) {
        const float* pp = params + ((size_t)b * TOPK + t) * 5;
        float muy = pp[0], mux = pp[1], dy = pp[2], dx = pp[3], p = pp[4];
        float cy = fmaxf(fmaxf((float)ty0 - muy, muy - (float)(ty0 + TILE - 1)), 0.0f);
        float cx = fmaxf(fmaxf((float)tx0 - mux, mux - (float)(tx0 + TILE - 1)), 0.0f);
        float zy = cy / fabsf(dy);
        float zx = cx / fabsf(dx);
        float z2 = zy * zy + zx * zx;
        if (!(z2 > 40.0f)) {                 // keep NaN cases
            int idx = atomicAdd(&cntS, 1);
            float* q = lp + idx * 5;
            q[0] = muy; q[1] = mux; q[2] = dy; q[3] = dx; q[4] = p;
        }
    }
    __syncthreads();
    int n = cntS;
    float py = (float)(ty0 + (tid >> 4));
    float px = (float)(tx0 + (tid & 15));
    float m = 0.0f;
    for (int t = 0; t < n; ++t) {
        float muy = lp[t * 5 + 0], mux = lp[t * 5 + 1];
        float dy = lp[t * 5 + 2], dx = lp[t * 5 + 3], p = lp[t * 5 + 4];
        float zy = (py - muy) / dy;
        float zx = (px - mux) / dx;
        float g = expf(-0.5f * (zy * zy + zx * zx)) * p;
        m = fmaxf(m, g);
    }
    heat[(size_t)b * NPIX + (ty0 + (tid >> 4)) * W + tx0 + (tid & 15)] = m;
}

extern "C" void kernel_launch(void* const* d_in, const int* in_sizes, int n_in,
                              void* d_out, int out_size, void* d_ws, size_t ws_size,
                              hipStream_t stream) {
    const float* mask = (const float*)d_in[0];
    const float* bias = (const float*)d_in[1];
    float* out = (float*)d_out;
    char* ws = (char*)d_ws;

    u64*   keys       = (u64*)(ws + KEY_OFF);
    int*   Fout       = (int*)(ws + F_OFF);
    float* cand_score = (float*)(ws + CSC_OFF);
    float* cand_box   = (float*)(ws + CBOX_OFF);
    u32*   sup        = (u32*)(ws + SUP_OFF);
    int*   NV         = (int*)(ws + NV_OFF);
    float* params     = (float*)(ws + PAR_OFF);
    unsigned char* flag = (unsigned char*)(ws + FLAG_OFF);
    int*   blkcnt     = (int*)(ws + BCNT_OFF);

    dim3 g100(NTILE, BATCH);
    k_score<<<g100, 256, 0, stream>>>(mask, keys, out + OUT_MASK_OFF, blkcnt);
    k_rankpad<<<g100, 256, 0, stream>>>(keys, bias, blkcnt, Fout, cand_score, cand_box);
    k_iou<<<dim3(PRE_K / 8, BATCH), 512, 0, stream>>>(cand_box, Fout, sup, flag);
    k_nmsfin<<<BATCH, 256, 0, stream>>>(sup, flag, Fout, cand_score, cand_box,
                                        out + OUT_BOX_OFF, out + OUT_VAL_OFF, params, NV);
    k_heat<<<g100, 256, 0, stream>>>(params, NV, out + OUT_HEAT_OFF);
}